// Round 1
// baseline (405.452 us; speedup 1.0000x reference)
//
#include <hip/hip_runtime.h>
#include <math.h>

#define BB 256
#define LL 512
#define DD 1024

// ---------------------------------------------------------------------------
// Kernel 1: hidden[b,d] = (1/L) * sum_l emb[tok[b,l]+1, d]
// One block per doc, 1024 threads = 4 groups of 256; each group sums 128 rows
// with float4 lanes, then LDS-reduce the 4 partials.
// ---------------------------------------------------------------------------
__global__ __launch_bounds__(1024) void k_hidden(const int* __restrict__ tokens,
                                                 const float* __restrict__ emb,
                                                 float* __restrict__ hidden) {
    __shared__ int   toks[LL];
    __shared__ float part[4][DD];
    const int b   = blockIdx.x;
    const int tid = threadIdx.x;

    if (tid < LL) toks[tid] = tokens[b * LL + tid] + 1;
    __syncthreads();

    const int g      = tid >> 8;       // group 0..3
    const int t256   = tid & 255;
    const int base_d = t256 * 4;

    float4 acc = make_float4(0.f, 0.f, 0.f, 0.f);
    #pragma unroll 4
    for (int i = 0; i < 128; ++i) {
        const int row = toks[g * 128 + i] * DD;
        const float4 e = *(const float4*)(emb + row + base_d);
        acc.x += e.x; acc.y += e.y; acc.z += e.z; acc.w += e.w;
    }
    *(float4*)(&part[g][base_d]) = acc;
    __syncthreads();

    // 1024 threads: one d each
    const float s = part[0][tid] + part[1][tid] + part[2][tid] + part[3][tid];
    hidden[b * DD + tid] = s * (1.0f / (float)LL);
}

// ---------------------------------------------------------------------------
// Kernel 2: q[b,d] = sum_e W[d,e] * hidden[b,e]   (q = hidden @ W^T)
// grid (D/64, B/4), block 256 (4 waves). Each block: 4 docs x 64 rows.
// W row chunks loaded once per row, dotted against 4 LDS-resident hiddens.
// ---------------------------------------------------------------------------
__global__ __launch_bounds__(256) void k_q(const float* __restrict__ hidden,
                                           const float* __restrict__ W,
                                           float* __restrict__ q) {
    __shared__ float hs[4][DD];
    const int dt  = blockIdx.x;   // 0..15
    const int bt  = blockIdx.y;   // 0..63
    const int tid = threadIdx.x;

    #pragma unroll
    for (int j = 0; j < 4; ++j)
        #pragma unroll
        for (int k = 0; k < 4; ++k)
            hs[j][k * 256 + tid] = hidden[(bt * 4 + j) * DD + k * 256 + tid];
    __syncthreads();

    const int w = tid >> 6, lane = tid & 63;

    for (int i = 0; i < 16; ++i) {
        const int d = dt * 64 + w * 16 + i;
        float a0 = 0.f, a1 = 0.f, a2 = 0.f, a3 = 0.f;
        #pragma unroll
        for (int k = 0; k < 4; ++k) {
            const int off = k * 256 + lane * 4;
            const float4 wv = *(const float4*)(W + d * DD + off);
            const float4 h0 = *(const float4*)(&hs[0][off]);
            const float4 h1 = *(const float4*)(&hs[1][off]);
            const float4 h2 = *(const float4*)(&hs[2][off]);
            const float4 h3 = *(const float4*)(&hs[3][off]);
            a0 += wv.x * h0.x + wv.y * h0.y + wv.z * h0.z + wv.w * h0.w;
            a1 += wv.x * h1.x + wv.y * h1.y + wv.z * h1.z + wv.w * h1.w;
            a2 += wv.x * h2.x + wv.y * h2.y + wv.z * h2.z + wv.w * h2.w;
            a3 += wv.x * h3.x + wv.y * h3.y + wv.z * h3.z + wv.w * h3.w;
        }
        #pragma unroll
        for (int m = 32; m; m >>= 1) {
            a0 += __shfl_xor(a0, m, 64);
            a1 += __shfl_xor(a1, m, 64);
            a2 += __shfl_xor(a2, m, 64);
            a3 += __shfl_xor(a3, m, 64);
        }
        if (lane == 0) {
            q[(bt * 4 + 0) * DD + d] = a0;
            q[(bt * 4 + 1) * DD + d] = a1;
            q[(bt * 4 + 2) * DD + d] = a2;
            q[(bt * 4 + 3) * DD + d] = a3;
        }
    }
}

// ---------------------------------------------------------------------------
// Kernel 3: fused scores -> online softmax -> ct, one block per doc.
// 512 threads = 8 waves; wave w owns tokens [w*64, w*64+64) with private
// online-softmax state; row stays in registers between the dot and the
// weighted accumulate (single gather read per row). Merge 8 waves via LDS.
// ---------------------------------------------------------------------------
__global__ __launch_bounds__(512) void k_attn(const int* __restrict__ tokens,
                                              const float* __restrict__ emb,
                                              const float* __restrict__ q,
                                              float* __restrict__ out) {
    __shared__ int   toks[LL];
    __shared__ float ctp[8][DD];
    __shared__ float mw[8], sw[8];

    const int b   = blockIdx.x;
    const int tid = threadIdx.x;
    if (tid < LL) toks[tid] = tokens[b * LL + tid] + 1;
    __syncthreads();

    const int w = tid >> 6, lane = tid & 63;

    float4 q4[4];
    #pragma unroll
    for (int c = 0; c < 4; ++c)
        q4[c] = *(const float4*)(q + b * DD + c * 256 + lane * 4);

    float m = -1e30f, s = 0.f;
    float4 ct[4];
    #pragma unroll
    for (int c = 0; c < 4; ++c) ct[c] = make_float4(0.f, 0.f, 0.f, 0.f);

    #pragma unroll 2
    for (int i = 0; i < 64; ++i) {
        const int l   = w * 64 + i;
        const int row = toks[l] * DD;
        float4 e4[4];
        #pragma unroll
        for (int c = 0; c < 4; ++c)
            e4[c] = *(const float4*)(emb + row + c * 256 + lane * 4);

        float p = 0.f;
        #pragma unroll
        for (int c = 0; c < 4; ++c)
            p += e4[c].x * q4[c].x + e4[c].y * q4[c].y +
                 e4[c].z * q4[c].z + e4[c].w * q4[c].w;
        #pragma unroll
        for (int mm = 32; mm; mm >>= 1) p += __shfl_xor(p, mm, 64);

        const float nm   = fmaxf(m, p);
        const float f    = __expf(m - nm);
        const float wexp = __expf(p - nm);
        s = s * f + wexp;
        #pragma unroll
        for (int c = 0; c < 4; ++c) {
            ct[c].x = ct[c].x * f + wexp * e4[c].x;
            ct[c].y = ct[c].y * f + wexp * e4[c].y;
            ct[c].z = ct[c].z * f + wexp * e4[c].z;
            ct[c].w = ct[c].w * f + wexp * e4[c].w;
        }
        m = nm;
    }

    #pragma unroll
    for (int c = 0; c < 4; ++c)
        *(float4*)(&ctp[w][c * 256 + lane * 4]) = ct[c];
    if (lane == 0) { mw[w] = m; sw[w] = s; }
    __syncthreads();

    // merge 8 wave-partials; each thread finalizes 2 d's
    float M = -1e30f;
    #pragma unroll
    for (int j = 0; j < 8; ++j) M = fmaxf(M, mw[j]);
    float denom = 0.f, sc[8];
    #pragma unroll
    for (int j = 0; j < 8; ++j) { sc[j] = __expf(mw[j] - M); denom += sc[j] * sw[j]; }
    const float inv = 1.0f / denom;

    #pragma unroll
    for (int r = 0; r < 2; ++r) {
        const int d = r * 512 + tid;
        float a = 0.f;
        #pragma unroll
        for (int j = 0; j < 8; ++j) a += sc[j] * ctp[j][d];
        out[b * DD + d] = a * inv;
    }
}

// ---------------------------------------------------------------------------
extern "C" void kernel_launch(void* const* d_in, const int* in_sizes, int n_in,
                              void* d_out, int out_size, void* d_ws, size_t ws_size,
                              hipStream_t stream) {
    const int*   tokens = (const int*)d_in[0];
    // d_in[1] = max_len (scalar), fixed to LL
    const float* emb    = (const float*)d_in[2];
    const float* W      = (const float*)d_in[3];
    float*       out    = (float*)d_out;

    float* hidden = (float*)d_ws;           // BB*DD floats = 1 MB
    float* q      = hidden + BB * DD;       // BB*DD floats = 1 MB

    k_hidden<<<BB, 1024, 0, stream>>>(tokens, emb, hidden);
    dim3 g2(DD / 64, BB / 4);
    k_q<<<g2, 256, 0, stream>>>(hidden, W, q);
    k_attn<<<BB, 512, 0, stream>>>(tokens, emb, q, out);
}